// Round 2
// baseline (495.432 us; speedup 1.0000x reference)
//
#include <hip/hip_runtime.h>
#include <stdint.h>

#define B_   16
#define N_   16128
#define C_   85
#define K_   500
#define KP   512
#define APB  128   // anchors per block in scores kernel

__device__ __forceinline__ float sigm(float x){ return 1.0f/(1.0f+__expf(-x)); }

// ---------------- Stage 1: scores[b][n] = max_c>=1 preds[b][n][c] ----------------
__global__ __launch_bounds__(256) void k_scores(const float* __restrict__ preds,
                                                float* __restrict__ scores){
  __shared__ float lds[APB*C_]; // 10880 floats = 43.5 KB
  const int tid = threadIdx.x;
  const size_t blockBase = (size_t)blockIdx.x * (APB*C_);
  const float4* g4 = (const float4*)(preds + blockBase);
  float4* l4 = (float4*)lds;
  const int NF4 = (APB*C_)/4; // 2720
  for (int f = tid; f < NF4; f += 256) l4[f] = g4[f];
  __syncthreads();
  if (tid < APB){
    const float* row = lds + tid*C_;
    float m = row[1];
    #pragma unroll
    for (int c=2; c<C_; ++c) m = fmaxf(m, row[c]);
    scores[(size_t)blockIdx.x*APB + tid] = m;
  }
}

// ---------------- Stage 2: exact top-500 (stable ties) + gather ----------------
// key = (score_bits << 32) | ~n  -> descending key == descending score, ties -> lowest n
__global__ __launch_bounds__(256) void k_topk(const float* __restrict__ scores,
                                              const float* __restrict__ boxes,
                                              const int*   __restrict__ targets,
                                              float* __restrict__ sscore,  // [B][K]
                                              float* __restrict__ gbox,    // [B][K][4]
                                              float* __restrict__ gtgt){   // [B][K]
  __shared__ unsigned int hist[256];
  __shared__ unsigned long long keybuf[KP];
  __shared__ unsigned long long s_pref;
  __shared__ unsigned long long s_pmask;
  __shared__ unsigned int s_k;
  __shared__ unsigned int s_cnt;
  const int img = blockIdx.x;
  const int tid = threadIdx.x;
  const float* sc = scores + (size_t)img*N_;

  if (tid==0){ s_pref = 0ULL; s_pmask = 0ULL; s_k = K_; s_cnt = 0; }
  __syncthreads();

  // radix-select the exact 500th-largest 64-bit key, high byte first
  for (int bp = 7; bp >= 0; --bp){
    hist[tid] = 0;
    __syncthreads();
    const unsigned long long pref  = s_pref;
    const unsigned long long pmask = s_pmask;
    for (int n = tid; n < N_; n += 256){
      unsigned int sb = __float_as_uint(sc[n]);
      unsigned long long key = ((unsigned long long)sb << 32) | (unsigned long long)(0xFFFFFFFFu - (unsigned)n);
      if ((key & pmask) == pref)
        atomicAdd(&hist[(unsigned)(key >> (unsigned)(bp*8)) & 255u], 1u);
    }
    __syncthreads();
    if (tid == 0){
      unsigned int kk = s_k, cum = 0; unsigned long long sel = 0;
      for (int d = 255; d >= 0; --d){
        unsigned int h = hist[d];
        if (cum + h >= kk){ sel = (unsigned long long)(unsigned)d; s_k = kk - cum; break; }
        cum += h;
      }
      s_pref  = s_pref  | (sel << (unsigned)(bp*8));
      s_pmask = s_pmask | (0xFFULL << (unsigned)(bp*8));
    }
    __syncthreads();
  }
  const unsigned long long T = s_pref;

  // compact all keys >= T (exactly 500, keys are unique)
  for (int n = tid; n < N_; n += 256){
    unsigned int sb = __float_as_uint(sc[n]);
    unsigned long long key = ((unsigned long long)sb << 32) | (unsigned long long)(0xFFFFFFFFu - (unsigned)n);
    if (key >= T){
      unsigned int pos = atomicAdd(&s_cnt, 1u);
      if (pos < KP) keybuf[pos] = key;
    }
  }
  __syncthreads();
  const unsigned int cnt = s_cnt;
  for (int i = tid; i < KP; i += 256) if (i >= (int)cnt) keybuf[i] = 0ULL;
  __syncthreads();

  // bitonic sort, descending by 64-bit key
  for (int k = 2; k <= KP; k <<= 1){
    for (int j = k >> 1; j > 0; j >>= 1){
      for (int i = tid; i < KP; i += 256){
        int ixj = i ^ j;
        if (ixj > i){
          unsigned long long a = keybuf[i], b = keybuf[ixj];
          bool desc = ((i & k) == 0);
          if (desc ? (a < b) : (a > b)){ keybuf[i] = b; keybuf[ixj] = a; }
        }
      }
      __syncthreads();
    }
  }

  for (int r = tid; r < K_; r += 256){
    unsigned long long key = keybuf[r];
    unsigned int sb = (unsigned int)(key >> 32);
    unsigned int n  = 0xFFFFFFFFu - (unsigned int)(key & 0xFFFFFFFFu);
    sscore[img*K_ + r] = __uint_as_float(sb);
    ((float4*)gbox)[img*K_ + r] = ((const float4*)boxes)[(size_t)img*N_ + n];
    gtgt[img*K_ + r] = (float)targets[(size_t)img*N_ + n];
  }
}

// ---------------- Stage 3+4: diff-NMS column sweep + AP loss, one block/image ----------------
__global__ __launch_bounds__(512) void k_nms_ap(const float* __restrict__ sscore,
                                                const float* __restrict__ gbox,
                                                const float* __restrict__ gtgt,
                                                float* __restrict__ lossimg){
  __shared__ float  Pl[16*KP];   // 32 KB: 16 prune rows (columns = threads)
  __shared__ float4 bxsh[KP];    // 8 KB
  __shared__ float  vsh[KP];
  __shared__ float  ysh[KP];
  __shared__ float  red[16];
  const int img = blockIdx.x;
  const int tid = threadIdx.x;

  float r = 0.0f;
  float4 bi = make_float4(0.f,0.f,0.f,0.f);
  if (tid < K_){
    r  = sscore[img*K_ + tid];
    bi = ((const float4*)gbox)[img*K_ + tid];
    ysh[tid] = gtgt[img*K_ + tid];
  } else {
    ysh[tid] = 0.0f;
  }
  bxsh[tid] = bi;
  vsh[tid]  = 0.0f;
  const float areai = fmaxf(bi.z-bi.x,0.f)*fmaxf(bi.w-bi.y,0.f);
  __syncthreads();

  // forward substitution: v_i = clip(s_i - sum_{j<i} P[j][i] * v_j, 0, 1)
  for (int j0 = 0; j0 < K_; j0 += 16){
    const int rows = min(16, K_ - j0);
    // compute prune chunk inline (IoU symmetric): Pl[rr][tid] = sigmoid((iou-0.4)/0.1)
    for (int rr = 0; rr < rows; ++rr){
      float4 bj = bxsh[j0+rr];
      float x1 = fmaxf(bj.x, bi.x), y1 = fmaxf(bj.y, bi.y);
      float x2 = fminf(bj.z, bi.z), y2 = fminf(bj.w, bi.w);
      float inter = fmaxf(x2-x1, 0.f) * fmaxf(y2-y1, 0.f);
      float areaj = fmaxf(bj.z-bj.x, 0.f) * fmaxf(bj.w-bj.y, 0.f);
      float uni = areai + areaj - inter;
      float iou = inter / fmaxf(uni, 1e-9f);
      Pl[rr*KP + tid] = sigm((iou - 0.4f) * 10.0f);
    }
    __syncthreads();
    for (int rr = 0; rr < rows; ++rr){
      const int j = j0 + rr;
      if (tid == j) vsh[j] = fminf(fmaxf(r, 0.0f), 1.0f);
      __syncthreads();
      if (tid > j && tid < K_) r -= Pl[rr*KP + tid] * vsh[j];
    }
    __syncthreads();
  }

  // AP loss: H[i][j] = sigmoid((v_j - v_i)/0.05), j != i
  const float vi = vsh[tid];
  const float yi = ysh[tid];
  float rank = 0.f, posr = 0.f;
  if (tid < K_){
    #pragma unroll 4
    for (int j = 0; j < K_; ++j){
      float h = sigm((vsh[j] - vi) * 20.0f);
      float m = (j == tid) ? 0.0f : 1.0f;
      rank += h * m;
      posr += h * ysh[j] * m;
    }
  }
  float contrib = 0.f, ypos = 0.f;
  if (tid < K_){
    float prec = (1.0f + posr) / (1.0f + rank);
    contrib = prec * yi;
    ypos = yi;
  }
  #pragma unroll
  for (int off = 32; off > 0; off >>= 1){
    contrib += __shfl_xor(contrib, off, 64);
    ypos    += __shfl_xor(ypos,    off, 64);
  }
  const int wv = tid >> 6, ln = tid & 63;
  if (ln == 0){ red[wv] = contrib; red[8+wv] = ypos; }
  __syncthreads();
  if (tid == 0){
    float tc = 0.f, tn = 0.f;
    for (int w = 0; w < 8; ++w){ tc += red[w]; tn += red[8+w]; }
    lossimg[img] = 1.0f - tc / fmaxf(tn, 1.0f);
  }
}

// ---------------- Stage 5: mean over images ----------------
__global__ void k_final(const float* __restrict__ lossimg, float* __restrict__ out){
  if (threadIdx.x == 0 && blockIdx.x == 0){
    float s = 0.f;
    for (int i = 0; i < B_; ++i) s += lossimg[i];
    out[0] = s * (1.0f/(float)B_);
  }
}

extern "C" void kernel_launch(void* const* d_in, const int* in_sizes, int n_in,
                              void* d_out, int out_size, void* d_ws, size_t ws_size,
                              hipStream_t stream){
  const float* preds   = (const float*)d_in[0];
  const float* boxes   = (const float*)d_in[1];
  const int*   targets = (const int*)d_in[2];
  float* out = (float*)d_out;

  char* ws = (char*)d_ws;
  size_t off = 0;
  auto alloc = [&](size_t nbytes)->void*{
    void* p = ws + off; off += (nbytes + 255) & ~(size_t)255; return p;
  };
  float* scores  = (float*)alloc((size_t)B_*N_*sizeof(float));
  float* sscore  = (float*)alloc((size_t)B_*K_*sizeof(float));
  float* gbox    = (float*)alloc((size_t)B_*K_*4*sizeof(float));
  float* gtgt    = (float*)alloc((size_t)B_*K_*sizeof(float));
  float* lossimg = (float*)alloc((size_t)B_*sizeof(float));

  k_scores<<<(B_*N_)/APB, 256, 0, stream>>>(preds, scores);
  k_topk  <<<B_,          256, 0, stream>>>(scores, boxes, targets, sscore, gbox, gtgt);
  k_nms_ap<<<B_,          512, 0, stream>>>(sscore, gbox, gtgt, lossimg);
  k_final <<<1,            64, 0, stream>>>(lossimg, out);
}